// Round 2
// 1440.488 us; speedup vs baseline: 1.3241x; 1.3241x over previous
//
#include <hip/hip_runtime.h>
#include <hip/hip_bf16.h>

#define NN 256
#define PP 2
#define LL 9
#define FF 64
#define NSLICE (NN * PP * LL)   // 4608 (b,p,l) slices per row
#define RS (NSLICE * FF)        // 294912 floats per row of x/G/V/out

typedef __attribute__((ext_vector_type(8))) short short8;   // 8 bf16 = 4 VGPRs
typedef __attribute__((ext_vector_type(4))) float f32x4;

// ---------------------------------------------------------------------------
// K1: M[p][f][h] = sum_g Wq[p][f][g] * Wk[p][h][g]   (M = Wq @ Wk^T per parity)
// ---------------------------------------------------------------------------
__global__ __launch_bounds__(256) void k_make_m(const float* __restrict__ Wq,
                                                const float* __restrict__ Wk,
                                                float* __restrict__ M) {
    int p = blockIdx.x;
    int t = threadIdx.x;
    const float* wq = Wq + p * FF * FF;
    const float* wk = Wk + p * FF * FF;
    float* m = M + p * FF * FF;
    for (int i = 0; i < 16; ++i) {
        int idx = t * 16 + i;
        int f = idx >> 6, h = idx & 63;
        float s = 0.f;
#pragma unroll 16
        for (int g = 0; g < FF; ++g) s += wq[f * FF + g] * wk[h * FF + g];
        m[idx] = s;
    }
}

// ---------------------------------------------------------------------------
// K2/K5a: per-parity feature projection.
// out[r][s*64+g] = sum_f x[r][s*64+f] * W[p(s)][f][g]
// grid = NSLICE*2 blocks: block handles slice s = bx>>1, row half (bx&1)*128.
// LDS: xs transposed [f][r] 32KB + W [f][g] 16KB = 48KB.
// ---------------------------------------------------------------------------
__global__ __launch_bounds__(256) void k_proj(const float* __restrict__ x,
                                              const float* __restrict__ W,
                                              float* __restrict__ out) {
    __shared__ float xs[FF][128];
    __shared__ float wl[FF][FF];
    int s = blockIdx.x >> 1;
    int rbase = (blockIdx.x & 1) * 128;
    int p = (s / LL) % PP;
    int t = threadIdx.x;

    // stage W[p] (4096 floats)
    {
        const float4* src = reinterpret_cast<const float4*>(W + p * FF * FF);
        float4* dst = reinterpret_cast<float4*>(&wl[0][0]);
#pragma unroll
        for (int i = 0; i < 4; ++i) dst[t + 256 * i] = src[t + 256 * i];
    }
    // stage x slice transposed: 128 rows x 64 f
    {
        int row = t & 127;
        int ch = t >> 7;  // which 32-f half
        const float4* rp = reinterpret_cast<const float4*>(
            x + (size_t)(rbase + row) * RS + (size_t)s * FF + ch * 32);
#pragma unroll
        for (int q = 0; q < 8; ++q) {
            float4 v = rp[q];
            int f = ch * 32 + q * 4;
            xs[f + 0][row] = v.x;
            xs[f + 1][row] = v.y;
            xs[f + 2][row] = v.z;
            xs[f + 3][row] = v.w;
        }
    }
    __syncthreads();

    int rq = t >> 2;  // 0..63 -> rows rq*2, rq*2+1
    int g4 = t & 3;   // 0..3  -> g in [g4*16, g4*16+16)
    float acc[2][16];
#pragma unroll
    for (int i = 0; i < 2; ++i)
#pragma unroll
        for (int j = 0; j < 16; ++j) acc[i][j] = 0.f;

#pragma unroll 4
    for (int f = 0; f < FF; ++f) {
        float2 xv = *reinterpret_cast<const float2*>(&xs[f][rq * 2]);
        float4 w0 = *reinterpret_cast<const float4*>(&wl[f][g4 * 16]);
        float4 w1 = *reinterpret_cast<const float4*>(&wl[f][g4 * 16 + 4]);
        float4 w2 = *reinterpret_cast<const float4*>(&wl[f][g4 * 16 + 8]);
        float4 w3 = *reinterpret_cast<const float4*>(&wl[f][g4 * 16 + 12]);
        float xa[2] = {xv.x, xv.y};
        float wg[16] = {w0.x, w0.y, w0.z, w0.w, w1.x, w1.y, w1.z, w1.w,
                        w2.x, w2.y, w2.z, w2.w, w3.x, w3.y, w3.z, w3.w};
#pragma unroll
        for (int i = 0; i < 2; ++i)
#pragma unroll
            for (int j = 0; j < 16; ++j) acc[i][j] += xa[i] * wg[j];
    }

#pragma unroll
    for (int i = 0; i < 2; ++i) {
        float* o = out + (size_t)(rbase + rq * 2 + i) * RS + (size_t)s * FF + g4 * 16;
        reinterpret_cast<float4*>(o)[0] = make_float4(acc[i][0], acc[i][1], acc[i][2], acc[i][3]);
        reinterpret_cast<float4*>(o)[1] = make_float4(acc[i][4], acc[i][5], acc[i][6], acc[i][7]);
        reinterpret_cast<float4*>(o)[2] = make_float4(acc[i][8], acc[i][9], acc[i][10], acc[i][11]);
        reinterpret_cast<float4*>(o)[3] = make_float4(acc[i][12], acc[i][13], acc[i][14], acc[i][15]);
    }
}

// ---------------------------------------------------------------------------
// K3: dot[a][c] += G[a][k] . x[c][k] via bf16-split MFMA.
// Each fp32 value v is split into hi = bf16(v), lo = bf16(v - hi); the dot is
// accumulated as Ahi*Bhi + Ahi*Blo + Alo*Bhi (3 mfma products, fp32 acc).
// Dropped lo*lo term ~2^-18 relative -> logit error ~0.002 (softmax-safe).
//
// Tile: 128 a x 256 c per block; grid (2 a-tiles, 128 k-chunks) -> 256 blocks,
// atomics identical in count/pattern to the previous fp32 version (8.4M).
// LDS rows are 128B: bf16 hi in bytes [0,64), lo in [64,128), XOR-swizzled
// byte ^= ((row&7)<<4) so ds_read_b128 fragment reads are ~2-way (free).
// Staging is reg-based (fp32->bf16 conversion), next chunk's global loads are
// issued right after the ds_writes so HBM latency hides under the MFMA phase.
// ---------------------------------------------------------------------------
#define KCH (RS / 128)  // 2304 columns per k-chunk
#define KSTEP 32
#define NSTEPS (KCH / KSTEP)  // 72

__device__ __forceinline__ unsigned short f2bf(float f) {
    unsigned u = __float_as_uint(f);
    unsigned r = (u + 0x7fffu + ((u >> 16) & 1u)) >> 16;  // RNE
    return (unsigned short)r;
}

__device__ __forceinline__ void hilo(float f, unsigned short& h, unsigned short& l) {
    h = f2bf(f);
    float hf = __uint_as_float(((unsigned)h) << 16);
    l = f2bf(f - hf);
}

__device__ __forceinline__ void cvt4(float4 v, uint2& hp, uint2& lp) {
    unsigned short h0, h1, h2, h3, l0, l1, l2, l3;
    hilo(v.x, h0, l0);
    hilo(v.y, h1, l1);
    hilo(v.z, h2, l2);
    hilo(v.w, h3, l3);
    hp.x = (unsigned)h0 | ((unsigned)h1 << 16);
    hp.y = (unsigned)h2 | ((unsigned)h3 << 16);
    lp.x = (unsigned)l0 | ((unsigned)l1 << 16);
    lp.y = (unsigned)l2 | ((unsigned)l3 << 16);
}

// byte address within a 128B-row tile, XOR-swizzled (bits 4..6)
__device__ __forceinline__ int swz(int row, int byteoff) {
    return row * 128 + (byteoff ^ ((row & 7) << 4));
}

__global__ __launch_bounds__(512) void k_dot_mfma(const float* __restrict__ G,
                                                  const float* __restrict__ x,
                                                  float* __restrict__ dotm) {
    __shared__ __align__(16) char GaB[128 * 128];  // 16 KB
    __shared__ __align__(16) char XaB[256 * 128];  // 32 KB
    const int a0 = blockIdx.x * 128;
    const size_t k0 = (size_t)blockIdx.y * KCH;
    const int t = threadIdx.x;
    const int lane = t & 63;
    const int w = t >> 6;      // wave 0..7 (2 x 4)
    const int wa = w >> 2;     // a-half 0..1 (64 rows)
    const int wc = w & 3;      // c-quarter 0..3 (64 cols)
    const int lrow = lane & 15;
    const int lg = lane >> 4;  // 0..3 -> k-block of 8

    // staging assignment: G 128 rows x 32 floats (4 thr/row x 2 float4),
    //                     x 256 rows x 32 floats (2 thr/row x 4 float4)
    const int grow = t >> 2;
    const int gq0 = (t & 3) * 2;
    const int xrow = t & 255;
    const int xq0 = (t >> 8) * 4;

    const float4* gsrc = reinterpret_cast<const float4*>(&G[(size_t)(a0 + grow) * RS + k0]);
    const float4* xsrc = reinterpret_cast<const float4*>(&x[(size_t)xrow * RS + k0]);

    f32x4 acc[4][4];
    const f32x4 zero = {0.f, 0.f, 0.f, 0.f};
#pragma unroll
    for (int i = 0; i < 4; ++i)
#pragma unroll
        for (int j = 0; j < 4; ++j) acc[i][j] = zero;

    float4 rg[2], rx[4];
#pragma unroll
    for (int q = 0; q < 2; ++q) rg[q] = gsrc[gq0 + q];
#pragma unroll
    for (int q = 0; q < 4; ++q) rx[q] = xsrc[xq0 + q];

    for (int st = 0; st < NSTEPS; ++st) {
        __syncthreads();  // prev compute done -> LDS reusable
        // convert staged regs -> hi/lo bf16, write to swizzled LDS
#pragma unroll
        for (int q = 0; q < 2; ++q) {
            uint2 hp, lp;
            cvt4(rg[q], hp, lp);
            int ko = (gq0 + q) * 4;  // 0..28
            *reinterpret_cast<uint2*>(&GaB[swz(grow, 2 * ko)]) = hp;
            *reinterpret_cast<uint2*>(&GaB[swz(grow, 64 + 2 * ko)]) = lp;
        }
#pragma unroll
        for (int q = 0; q < 4; ++q) {
            uint2 hp, lp;
            cvt4(rx[q], hp, lp);
            int ko = (xq0 + q) * 4;
            *reinterpret_cast<uint2*>(&XaB[swz(xrow, 2 * ko)]) = hp;
            *reinterpret_cast<uint2*>(&XaB[swz(xrow, 64 + 2 * ko)]) = lp;
        }
        // issue next chunk's global loads now; results not needed until
        // next iteration's ds_write -> latency hides under MFMA below
        if (st + 1 < NSTEPS) {
            int f4b = (st + 1) * 8;
#pragma unroll
            for (int q = 0; q < 2; ++q) rg[q] = gsrc[f4b + gq0 + q];
#pragma unroll
            for (int q = 0; q < 4; ++q) rx[q] = xsrc[f4b + xq0 + q];
        }
        __syncthreads();  // LDS tiles ready

        short8 bh[4], bl[4];
#pragma unroll
        for (int j = 0; j < 4; ++j) {
            int c = wc * 64 + j * 16 + lrow;
            bh[j] = *reinterpret_cast<const short8*>(&XaB[swz(c, lg * 16)]);
            bl[j] = *reinterpret_cast<const short8*>(&XaB[swz(c, 64 + lg * 16)]);
        }
#pragma unroll
        for (int i = 0; i < 4; ++i) {
            int r = wa * 64 + i * 16 + lrow;
            short8 ah = *reinterpret_cast<const short8*>(&GaB[swz(r, lg * 16)]);
            short8 al = *reinterpret_cast<const short8*>(&GaB[swz(r, 64 + lg * 16)]);
#pragma unroll
            for (int j = 0; j < 4; ++j) {
                acc[i][j] = __builtin_amdgcn_mfma_f32_16x16x32_bf16(ah, bh[j], acc[i][j], 0, 0, 0);
                acc[i][j] = __builtin_amdgcn_mfma_f32_16x16x32_bf16(ah, bl[j], acc[i][j], 0, 0, 0);
                acc[i][j] = __builtin_amdgcn_mfma_f32_16x16x32_bf16(al, bh[j], acc[i][j], 0, 0, 0);
            }
        }
    }

    // epilogue: D frag mapping (m89-verified): col = lane&15, row = (lane>>4)*4 + reg
#pragma unroll
    for (int i = 0; i < 4; ++i) {
        int abase = a0 + wa * 64 + i * 16 + lg * 4;
#pragma unroll
        for (int j = 0; j < 4; ++j) {
            int c = wc * 64 + j * 16 + lrow;
#pragma unroll
            for (int r = 0; r < 4; ++r)
                atomicAdd(&dotm[(abase + r) * NN + c], acc[i][j][r]);
        }
    }
}

// ---------------------------------------------------------------------------
// K4: column softmax (softmax over a for each column b), writing TRANSPOSED:
// Wt[b][a] = exp(dot[a][b]-max_a)/sum_a
// ---------------------------------------------------------------------------
__global__ __launch_bounds__(256) void k_softmax(const float* __restrict__ dotm,
                                                 float* __restrict__ Wt) {
    __shared__ float red[256];
    int b = blockIdx.x, t = threadIdx.x;
    float v = dotm[t * NN + b];
    red[t] = v;
    __syncthreads();
    for (int st = 128; st > 0; st >>= 1) {
        if (t < st) red[t] = fmaxf(red[t], red[t + st]);
        __syncthreads();
    }
    float m = red[0];
    __syncthreads();
    float e = __expf(v - m);
    red[t] = e;
    __syncthreads();
    for (int st = 128; st > 0; st >>= 1) {
        if (t < st) red[t] += red[t + st];
        __syncthreads();
    }
    float inv = 1.0f / red[0];
    Wt[b * NN + t] = e * inv;
}

// ---------------------------------------------------------------------------
// K5b: out[a][s*64+g] = sum_b Wt[b][a] * V[b][s*64+g], IN PLACE over V (=VO).
// ---------------------------------------------------------------------------
__global__ __launch_bounds__(256) void k_out(float* __restrict__ VO,
                                             const float* __restrict__ Wt) {
    __shared__ __hip_bfloat16 Vs[NN][72];
    __shared__ __hip_bfloat16 Wc[32][264];
    int s = blockIdx.x;
    int t = threadIdx.x;

    // stage V stripe row b=t, fp32 -> bf16
    {
        const float4* vr = reinterpret_cast<const float4*>(VO + (size_t)t * RS + (size_t)s * FF);
#pragma unroll
        for (int q = 0; q < 8; ++q) {
            float4 v0 = vr[q * 2];
            float4 v1 = vr[q * 2 + 1];
            union { float4 f; __hip_bfloat16 h[8]; } u;
            u.h[0] = __float2bfloat16(v0.x); u.h[1] = __float2bfloat16(v0.y);
            u.h[2] = __float2bfloat16(v0.z); u.h[3] = __float2bfloat16(v0.w);
            u.h[4] = __float2bfloat16(v1.x); u.h[5] = __float2bfloat16(v1.y);
            u.h[6] = __float2bfloat16(v1.z); u.h[7] = __float2bfloat16(v1.w);
            *reinterpret_cast<float4*>(&Vs[t][q * 8]) = u.f;
        }
    }

    int ta = t >> 3;  // 0..31 -> a = ta*8 + i
    int tg = t & 7;   // 0..7  -> g = tg*8 + j
    float acc[8][8];
#pragma unroll
    for (int i = 0; i < 8; ++i)
#pragma unroll
        for (int j = 0; j < 8; ++j) acc[i][j] = 0.f;

    for (int bc = 0; bc < 8; ++bc) {
        __syncthreads();  // first iter: Vs staged; later: prev compute done
        {
            int row = t >> 3;  // 0..31
            int e8 = t & 7;    // 32-float piece of the 256-wide row
            const float4* wr = reinterpret_cast<const float4*>(
                Wt + (size_t)(bc * 32 + row) * NN + e8 * 32);
#pragma unroll
            for (int q = 0; q < 4; ++q) {
                float4 v0 = wr[q * 2];
                float4 v1 = wr[q * 2 + 1];
                union { float4 f; __hip_bfloat16 h[8]; } u;
                u.h[0] = __float2bfloat16(v0.x); u.h[1] = __float2bfloat16(v0.y);
                u.h[2] = __float2bfloat16(v0.z); u.h[3] = __float2bfloat16(v0.w);
                u.h[4] = __float2bfloat16(v1.x); u.h[5] = __float2bfloat16(v1.y);
                u.h[6] = __float2bfloat16(v1.z); u.h[7] = __float2bfloat16(v1.w);
                *reinterpret_cast<float4*>(&Wc[row][e8 * 32 + q * 8]) = u.f;
            }
        }
        __syncthreads();
#pragma unroll 2
        for (int bb = 0; bb < 32; ++bb) {
            int b = bc * 32 + bb;
            float4 wraw = *reinterpret_cast<const float4*>(&Wc[bb][ta * 8]);
            float4 vraw = *reinterpret_cast<const float4*>(&Vs[b][tg * 8]);
            const __hip_bfloat162* wp = reinterpret_cast<const __hip_bfloat162*>(&wraw);
            const __hip_bfloat162* vp = reinterpret_cast<const __hip_bfloat162*>(&vraw);
            float2 w0 = __bfloat1622float2(wp[0]);
            float2 w1 = __bfloat1622float2(wp[1]);
            float2 w2 = __bfloat1622float2(wp[2]);
            float2 w3 = __bfloat1622float2(wp[3]);
            float2 v0 = __bfloat1622float2(vp[0]);
            float2 v1 = __bfloat1622float2(vp[1]);
            float2 v2 = __bfloat1622float2(vp[2]);
            float2 v3 = __bfloat1622float2(vp[3]);
            float wv[8] = {w0.x, w0.y, w1.x, w1.y, w2.x, w2.y, w3.x, w3.y};
            float vv[8] = {v0.x, v0.y, v1.x, v1.y, v2.x, v2.y, v3.x, v3.y};
#pragma unroll
            for (int i = 0; i < 8; ++i)
#pragma unroll
                for (int j = 0; j < 8; ++j) acc[i][j] += wv[i] * vv[j];
        }
    }

#pragma unroll
    for (int i = 0; i < 8; ++i) {
        float* o = VO + (size_t)(ta * 8 + i) * RS + (size_t)s * FF + tg * 8;
        *reinterpret_cast<float4*>(o) = make_float4(acc[i][0], acc[i][1], acc[i][2], acc[i][3]);
        *reinterpret_cast<float4*>(o + 4) = make_float4(acc[i][4], acc[i][5], acc[i][6], acc[i][7]);
    }
}

// ---------------------------------------------------------------------------
extern "C" void kernel_launch(void* const* d_in, const int* in_sizes, int n_in,
                              void* d_out, int out_size, void* d_ws, size_t ws_size,
                              hipStream_t stream) {
    const float* x = (const float*)d_in[0];
    const float* Wq = (const float*)d_in[1];
    const float* Wk = (const float*)d_in[2];
    const float* Wv = (const float*)d_in[3];
    float* out = (float*)d_out;

    float* M = (float*)d_ws;                 // 2*64*64      =  8192 floats
    float* dotm = M + PP * FF * FF;          // 256*256      = 65536 floats
    float* Wt = dotm + NN * NN;              // 256*256      = 65536 floats

    // M = Wq @ Wk^T per parity
    k_make_m<<<PP, 256, 0, stream>>>(Wq, Wk, M);
    // G = x @ M  (into d_out as scratch)
    k_proj<<<NSLICE * 2, 256, 0, stream>>>(x, M, out);
    // dot = G . x^T  (split-K, bf16-split MFMA, fp32 atomics)
    hipMemsetAsync(dotm, 0, NN * NN * sizeof(float), stream);
    k_dot_mfma<<<dim3(2, 128), 512, 0, stream>>>(out, x, dotm);
    // weights (transposed) = column-softmax(dot)
    k_softmax<<<NN, 256, 0, stream>>>(dotm, Wt);
    // V = x @ Wv (into d_out, overwriting G)
    k_proj<<<NSLICE * 2, 256, 0, stream>>>(x, Wv, out);
    // out = Wt-weighted mix of V, in place
    k_out<<<NSLICE, 256, 0, stream>>>(out, Wt);
}